// Round 6
// baseline (144.455 us; speedup 1.0000x reference)
//
#include <hip/hip_runtime.h>
#include <hip/hip_fp16.h>

// FactoredBlock: out[n,:] = sum_{k in row n} values[k] * weights[f_table[active_idx[k]], :]
// batch_idx sorted. Strategy: weights live in LDS (f16), K-sliced.
//   build_a: CSR offsets + per-(row,slice) bucket counts + W f32->f16 split
//            into two column planes (A: cols 8k..8k+3, B: cols 8k+4..8k+7)
//   build_b: per-row bucket prefix -> bstart[N*9]; init fill counters
//   build_c: scatter pairs {f_local:16 | f16(v):16} into bucketed bp[]
//   gemm   : 256 blocks x 512 thr (1/CU). For each of 8 K-slices: stage
//            96x256 f16 W slice (48 KB) into LDS, each wave processes 8 rows'
//            bucket-s pairs: 2 nnz per step (lanes<32 even, >=32 odd),
//            2x ds_read_b64 per nnz (2-way bank alias = free), hfma2 acc,
//            shfl_xor(32) combine, f32 store. Pairs staged in LDS (13 KB).

#define OUT_COLS 256
#define INTER 768
#define SLICES 8
#define SROWS 96                 // INTER / SLICES
#define BROWS 64                 // rows per gemm block
#define GEMM_THREADS 512
#define PS_CAP 3392              // pairs LDS capacity (avg block ~2048, +30 sigma)
#define NWEL (INTER * OUT_COLS)  // weight elements

__device__ __forceinline__ unsigned f16bits(float x) {
    return (unsigned)__half_as_ushort(__float2half(x));
}

// ---------------- build_a: offsets + bucket counts + W convert/split ----------------
__global__ __launch_bounds__(256)
void build_a(const int* __restrict__ bi, const int* __restrict__ ai,
             const int* __restrict__ ft, const float* __restrict__ w,
             int* __restrict__ offsets, unsigned* __restrict__ cnt,
             unsigned short* __restrict__ whA, unsigned short* __restrict__ whB,
             int nnz, int N)
{
    const int k = blockIdx.x * 256 + threadIdx.x;
    if (k < NWEL) {
        const int f = k >> 8, c = k & 255;
        const unsigned short h = (unsigned short)f16bits(w[k]);
        const int idx = f * 128 + ((c >> 3) << 2) + (c & 3);
        if ((c >> 2) & 1) whB[idx] = h; else whA[idx] = h;
    }
    if (k >= nnz) return;
    const int r  = bi[k];
    const int rp = (k == 0) ? -1 : bi[k - 1];
    for (int row = rp + 1; row <= r; ++row) offsets[row] = k;
    if (k == nnz - 1)
        for (int row = r + 1; row <= N; ++row) offsets[row] = nnz;
    const int f = ft[ai[k]];
    const int s = (f * 683) >> 16;           // f / 96 for f < 768
    atomicAdd(&cnt[r * 8 + s], 1u);
}

// ---------------- build_b: per-row bucket prefix ----------------
__global__ __launch_bounds__(256)
void build_b(const int* __restrict__ offsets, unsigned* __restrict__ cnt,
             int* __restrict__ bstart, int N)
{
    const int r = blockIdx.x * 256 + threadIdx.x;
    if (r >= N) return;
    int acc = offsets[r];
#pragma unroll
    for (int s = 0; s < 8; ++s) {
        bstart[r * 9 + s] = acc;
        const unsigned c = cnt[r * 8 + s];
        cnt[r * 8 + s] = (unsigned)acc;      // becomes fill counter
        acc += (int)c;
    }
    bstart[r * 9 + 8] = acc;                 // == offsets[r+1]
}

// ---------------- build_c: scatter bucketed pairs ----------------
__global__ __launch_bounds__(256)
void build_c(const int* __restrict__ bi, const int* __restrict__ ai,
             const float* __restrict__ vals, const int* __restrict__ ft,
             unsigned* __restrict__ cnt, unsigned* __restrict__ bp, int nnz)
{
    const int k = blockIdx.x * 256 + threadIdx.x;
    if (k >= nnz) return;
    const int r = bi[k];
    const int f = ft[ai[k]];
    const int s = (f * 683) >> 16;
    const int fl = f - s * SROWS;            // local row within slice, < 96
    const unsigned dst = atomicAdd(&cnt[r * 8 + s], 1u);
    bp[dst] = ((unsigned)fl << 16) | f16bits(vals[k]);
}

// ---------------- gemm: LDS-resident W slices ----------------
__global__ __launch_bounds__(GEMM_THREADS)
void gemm_kernel(const int* __restrict__ offsets, const int* __restrict__ bstart,
                 const unsigned* __restrict__ bp,
                 const unsigned short* __restrict__ whA,
                 const unsigned short* __restrict__ whB,
                 float* __restrict__ out, int N)
{
    __shared__ __align__(16) unsigned short WsA[SROWS * 128];  // 24 KB
    __shared__ __align__(16) unsigned short WsB[SROWS * 128];  // 24 KB
    __shared__ __align__(16) unsigned Ps[PS_CAP];              // 13.25 KB
    __shared__ int ls[BROWS * 9];                              // 2.25 KB

    const int t    = threadIdx.x;
    const int lane = t & 63;
    const int wave = t >> 6;                 // 0..7
    const int r0   = blockIdx.x * BROWS;
    const int nrows = min(BROWS, N - r0);

    const int base = offsets[r0];
    const int tot  = offsets[r0 + nrows] - base;

    for (int i = t; i < nrows * 9; i += GEMM_THREADS)
        ls[i] = bstart[r0 * 9 + i] - base;
    const bool inlds = (tot <= PS_CAP);
    if (inlds)
        for (int i = t; i < tot; i += GEMM_THREADS) Ps[i] = bp[base + i];

    __half2 acc[8][4];
#pragma unroll
    for (int rr = 0; rr < 8; ++rr)
        acc[rr][0] = acc[rr][1] = acc[rr][2] = acc[rr][3] = __float2half2_rn(0.f);

    const int colh = (lane & 31) << 2;       // half-offset within 128-wide plane row
    const bool lo  = (lane < 32);

    auto slice_body = [&](const unsigned* pp, int s) {
        int js[8], je[8];
#pragma unroll
        for (int rr = 0; rr < 8; ++rr) {
            const int r = wave * 8 + rr;
            if (r < nrows) { js[rr] = ls[r * 9 + s]; je[rr] = ls[r * 9 + s + 1]; }
            else           { js[rr] = 0;             je[rr] = 0; }
        }
#pragma unroll
        for (int rr = 0; rr < 8; ++rr) {
            int j = js[rr];
            const int e = je[rr];
            for (; j < e; j += 4) {
                const unsigned p0 = pp[j];
                const unsigned p1 = (j + 1 < e) ? pp[j + 1] : 0u;
                const unsigned p2 = (j + 2 < e) ? pp[j + 2] : 0u;
                const unsigned p3 = (j + 3 < e) ? pp[j + 3] : 0u;
                const unsigned pa = lo ? p0 : p1;
                const unsigned pb = lo ? p2 : p3;
                const int fa = (int)(pa >> 16), fb = (int)(pb >> 16);
                const uint2 wa0 = *(const uint2*)&WsA[fa * 128 + colh];
                const uint2 wb0 = *(const uint2*)&WsB[fa * 128 + colh];
                const uint2 wa1 = *(const uint2*)&WsA[fb * 128 + colh];
                const uint2 wb1 = *(const uint2*)&WsB[fb * 128 + colh];
                unsigned va = pa & 0xffffu; va |= va << 16;
                unsigned vb = pb & 0xffffu; vb |= vb << 16;
                const __half2 hva = *(const __half2*)&va;
                const __half2 hvb = *(const __half2*)&vb;
                acc[rr][0] = __hfma2(*(const __half2*)&wa0.x, hva, acc[rr][0]);
                acc[rr][1] = __hfma2(*(const __half2*)&wa0.y, hva, acc[rr][1]);
                acc[rr][2] = __hfma2(*(const __half2*)&wb0.x, hva, acc[rr][2]);
                acc[rr][3] = __hfma2(*(const __half2*)&wb0.y, hva, acc[rr][3]);
                acc[rr][0] = __hfma2(*(const __half2*)&wa1.x, hvb, acc[rr][0]);
                acc[rr][1] = __hfma2(*(const __half2*)&wa1.y, hvb, acc[rr][1]);
                acc[rr][2] = __hfma2(*(const __half2*)&wb1.x, hvb, acc[rr][2]);
                acc[rr][3] = __hfma2(*(const __half2*)&wb1.y, hvb, acc[rr][3]);
            }
        }
    };

    for (int s = 0; s < SLICES; ++s) {
        const uint4* gA = (const uint4*)(whA + s * (SROWS * 128));
        const uint4* gB = (const uint4*)(whB + s * (SROWS * 128));
        uint4* sA = (uint4*)WsA;
        uint4* sB = (uint4*)WsB;
        for (int i = t; i < (SROWS * 128) / 8; i += GEMM_THREADS) {
            sA[i] = gA[i];
            sB[i] = gB[i];
        }
        __syncthreads();
        if (inlds) slice_body(Ps, s);
        else       slice_body(bp + base, s);
        __syncthreads();
    }

#pragma unroll
    for (int rr = 0; rr < 8; ++rr) {
        const int r = wave * 8 + rr;
        if (r >= nrows) continue;
        __half2 a0 = acc[rr][0], a1 = acc[rr][1], a2 = acc[rr][2], a3 = acc[rr][3];
        const int b0 = __shfl_xor(*(const int*)&a0, 32);
        const int b1 = __shfl_xor(*(const int*)&a1, 32);
        const int b2 = __shfl_xor(*(const int*)&a2, 32);
        const int b3 = __shfl_xor(*(const int*)&a3, 32);
        a0 = __hadd2(a0, *(const __half2*)&b0);
        a1 = __hadd2(a1, *(const __half2*)&b1);
        a2 = __hadd2(a2, *(const __half2*)&b2);
        a3 = __hadd2(a3, *(const __half2*)&b3);
        if (lo) {
            float4 o0, o1;
            o0.x = __low2float(a0); o0.y = __high2float(a0);
            o0.z = __low2float(a1); o0.w = __high2float(a1);
            o1.x = __low2float(a2); o1.y = __high2float(a2);
            o1.z = __low2float(a3); o1.w = __high2float(a3);
            float* orow = out + (size_t)(r0 + r) * OUT_COLS + ((lane & 31) << 3);
            *(float4*)orow = o0;
            *(float4*)(orow + 4) = o1;
        }
    }
}

// ---------------- fallback (binary search, f32 weights), if ws too small ----------------
__global__ __launch_bounds__(256, 8)
void fallback_kernel(const int* __restrict__ batch_idx,
                     const int* __restrict__ active_idx,
                     const float* __restrict__ values,
                     const int* __restrict__ f_table,
                     const float* __restrict__ weights,
                     float* __restrict__ out,
                     int nnz, int N)
{
    const int wave = threadIdx.x >> 6;
    const int lane = threadIdx.x & 63;
    const int row  = blockIdx.x * 4 + wave;
    if (row >= N) return;

    int lo1 = 0, hi1 = nnz, lo2 = 0, hi2 = nnz;
    while ((lo1 < hi1) | (lo2 < hi2)) {
        if (lo1 < hi1) { int m = (lo1 + hi1) >> 1; if (batch_idx[m] < row) lo1 = m + 1; else hi1 = m; }
        if (lo2 < hi2) { int m = (lo2 + hi2) >> 1; if (batch_idx[m] < row + 1) lo2 = m + 1; else hi2 = m; }
    }
    float4 acc = make_float4(0.f, 0.f, 0.f, 0.f);
    const float* __restrict__ wcol = weights + (lane << 2);
    for (int b = lo1; b < lo2; b += 64) {
        const int cnt = min(lo2 - b, 64);
        float v_l = 0.f; int f_l = 0;
        if (lane < cnt) { const int k = b + lane; v_l = values[k]; f_l = f_table[active_idx[k]]; }
        for (int j = 0; j < cnt; ++j) {
            const float v = __shfl(v_l, j);
            const int   f = __shfl(f_l, j);
            const float4 w = *(const float4*)(wcol + f * OUT_COLS);
            acc.x = fmaf(v, w.x, acc.x);
            acc.y = fmaf(v, w.y, acc.y);
            acc.z = fmaf(v, w.z, acc.z);
            acc.w = fmaf(v, w.w, acc.w);
        }
    }
    *(float4*)(out + row * OUT_COLS + (lane << 2)) = acc;
}

extern "C" void kernel_launch(void* const* d_in, const int* in_sizes, int n_in,
                              void* d_out, int out_size, void* d_ws, size_t ws_size,
                              hipStream_t stream) {
    const int*   batch_idx  = (const int*)d_in[0];
    const int*   active_idx = (const int*)d_in[1];
    const float* values     = (const float*)d_in[2];
    const int*   f_table    = (const int*)d_in[3];
    const float* weights    = (const float*)d_in[4];
    float*       out        = (float*)d_out;

    const int nnz = in_sizes[0];
    const int N   = out_size / OUT_COLS;     // 16384

    // ws layout (16 B aligned): offsets[N+1] | cnt[N*8] | bstart[N*9] |
    //                           whA[NWEL/2] f16 | whB[NWEL/2] f16 | bp[nnz]
    const size_t a16 = 15;
    const size_t off_off    = 0;
    const size_t cnt_off    = (off_off + (size_t)(N + 1) * 4 + a16) & ~a16;
    const size_t bstart_off = (cnt_off + (size_t)N * 8 * 4 + a16) & ~a16;
    const size_t whA_off    = (bstart_off + (size_t)N * 9 * 4 + a16) & ~a16;
    const size_t whB_off    = (whA_off + (size_t)(NWEL / 2) * 2 + a16) & ~a16;
    const size_t bp_off     = (whB_off + (size_t)(NWEL / 2) * 2 + a16) & ~a16;
    const size_t need       = bp_off + (size_t)nnz * 4 + 64;

    if (ws_size >= need) {
        int*            offsets = (int*)((char*)d_ws + off_off);
        unsigned*       cnt     = (unsigned*)((char*)d_ws + cnt_off);
        int*            bstart  = (int*)((char*)d_ws + bstart_off);
        unsigned short* whA     = (unsigned short*)((char*)d_ws + whA_off);
        unsigned short* whB     = (unsigned short*)((char*)d_ws + whB_off);
        unsigned*       bp      = (unsigned*)((char*)d_ws + bp_off);

        hipMemsetAsync(cnt, 0, (size_t)N * 8 * 4, stream);

        const int work_a = (nnz > NWEL) ? nnz : NWEL;
        build_a<<<(work_a + 255) / 256, 256, 0, stream>>>(
            batch_idx, active_idx, f_table, weights, offsets, cnt, whA, whB, nnz, N);
        build_b<<<(N + 255) / 256, 256, 0, stream>>>(offsets, cnt, bstart, N);
        build_c<<<(nnz + 255) / 256, 256, 0, stream>>>(
            batch_idx, active_idx, values, f_table, cnt, bp, nnz);
        gemm_kernel<<<(N + BROWS - 1) / BROWS, GEMM_THREADS, 0, stream>>>(
            offsets, bstart, bp, whA, whB, out, N);
    } else {
        fallback_kernel<<<(N + 3) / 4, 256, 0, stream>>>(
            batch_idx, active_idx, values, f_table, weights, out, nnz, N);
    }
}

// Round 7
// 90.673 us; speedup vs baseline: 1.5931x; 1.5931x over previous
//
#include <hip/hip_runtime.h>
#include <hip/hip_fp16.h>

// FactoredBlock: out[n,:] = sum_{k in row n} values[k] * weights[f_table[active_idx[k]], :]
// batch_idx sorted. Two dispatches:
//   build_kernel: fused (weights f32->f16) + CSR offsets[N+1] + packed pairs
//                 u32 {f:16 | f16bits(v):16}
//   gemm_kernel : 1 wave/row. Dual-row weight loads (lanes<32 -> nnz 2b,
//                 lanes>=32 -> nnz 2b+1; 16 B/lane = two 512 B f16 rows per
//                 instr). KEY r7 change: pairs fetched via ONE vector load
//                 (pairs[start+lane]) + ds_bpermute per batch -- the r2-r5
//                 inner loops compiled pair fetches to s_load (scalar L1
//                 thrash + lgkmcnt(0) serialization); no scalar mem in loop.

#define OUT_COLS 256
#define WAVES_PER_BLOCK 4
#define BLOCK_THREADS (WAVES_PER_BLOCK * 64)
#define NW (768 * 256)   // weight elements

// ---------------- phase A: convert weights + offsets + packed pairs ----------------
__global__ __launch_bounds__(256)
void build_kernel(const int* __restrict__ batch_idx,
                  const int* __restrict__ active_idx,
                  const float* __restrict__ values,
                  const int* __restrict__ f_table,
                  const float* __restrict__ weights,
                  int* __restrict__ offsets,            // [N+1]
                  unsigned* __restrict__ pairs,         // [nnz]
                  __half* __restrict__ wh,              // [NW]
                  int nnz, int N)
{
    const int k = blockIdx.x * 256 + threadIdx.x;
    if (k < NW) wh[k] = __float2half(weights[k]);
    if (k >= nnz) return;
    const int r  = batch_idx[k];
    const int rp = (k == 0) ? -1 : batch_idx[k - 1];
    for (int row = rp + 1; row <= r; ++row) offsets[row] = k;   // lower_bound fill
    if (k == nnz - 1)
        for (int row = r + 1; row <= N; ++row) offsets[row] = nnz;
    const unsigned f = (unsigned)f_table[active_idx[k]];        // < 768
    pairs[k] = (f << 16) | (unsigned)__half_as_ushort(__float2half(values[k]));
}

// ---------------- phase B: accumulate (1 wave/row, all-vector memory path) ----------------
__global__ __launch_bounds__(BLOCK_THREADS, 8)
void gemm_kernel(const int* __restrict__ offsets,
                 const unsigned* __restrict__ pairs,
                 const __half* __restrict__ wh,
                 float* __restrict__ out, int N)
{
    const int lane = threadIdx.x & 63;
    const int row  = blockIdx.x * WAVES_PER_BLOCK + (threadIdx.x >> 6);
    if (row >= N) return;

    // Bounds via VECTOR load (lane-dependent index defeats s_load promotion),
    // then broadcast. offsets[row] in lane0-path, offsets[row+1] in lane1-path.
    const int off_v = offsets[row + (lane & 1)];
    const int start = __shfl(off_v, 0);
    const int end   = __shfl(off_v, 1);
    const int cnt   = end - start;

    // One vector load covers up to 64 pairs of this row (rows >64 nnz: rare tail).
    const unsigned praw = pairs[start + lane];          // over-read slack in ws

    const int vhi  = lane >> 5;                         // 0: even nnz, 1: odd nnz
    const int vhi4 = vhi << 2;
    const __half* __restrict__ wcol = wh + ((lane & 31) << 3);  // 8 f16 cols/lane

    const __half2 zero = __float2half2_rn(0.0f);
    __half2 acc0 = zero, acc1 = zero, acc2 = zero, acc3 = zero;

    const int nb = (min(cnt, 64) + 1) >> 1;             // 2 nnz per batch

#pragma unroll 4
    for (int b = 0; b < nb; ++b) {
        const int idx = 2 * b + vhi;
        int pb = __builtin_amdgcn_ds_bpermute(vhi4 + (b << 3), (int)praw);
        pb = (idx < cnt) ? pb : 0;                      // mask pad nnz
        const unsigned up = (unsigned)pb;
        const uint4 wv = *(const uint4*)((const char*)wcol + ((up >> 16) << 9));
        unsigned vvu = (up & 0xffffu) | (up << 16);     // f16(v) in both halves
        const __half2 vv = *(const __half2*)&vvu;
        const __half2* w2 = (const __half2*)&wv;
        acc0 = __hfma2(w2[0], vv, acc0);
        acc1 = __hfma2(w2[1], vv, acc1);
        acc2 = __hfma2(w2[2], vv, acc2);
        acc3 = __hfma2(w2[3], vv, acc3);
    }

    // Rare tail for rows with >64 nnz: lo half only (hi zeroed to avoid double count)
    for (int k = start + 64; k < end; ++k) {
        unsigned p = pairs[k];
        if (vhi) p = 0;
        const uint4 wv = *(const uint4*)((const char*)wcol + ((p >> 16) << 9));
        unsigned vvu = (p & 0xffffu) | (p << 16);
        const __half2 vv = *(const __half2*)&vvu;
        const __half2* w2 = (const __half2*)&wv;
        acc0 = __hfma2(w2[0], vv, acc0);
        acc1 = __hfma2(w2[1], vv, acc1);
        acc2 = __hfma2(w2[2], vv, acc2);
        acc3 = __hfma2(w2[3], vv, acc3);
    }

    // combine even/odd halves: lane l and l+32 hold the same 8 cols
    __half2 accs[4] = {acc0, acc1, acc2, acc3};
#pragma unroll
    for (int i = 0; i < 4; ++i) {
        int a = *(const int*)&accs[i];
        const int b = __shfl_xor(a, 32);
        accs[i] = __hadd2(accs[i], *(const __half2*)&b);
    }
    if (vhi == 0) {
        float4 o0, o1;
        o0.x = __low2float(accs[0]); o0.y = __high2float(accs[0]);
        o0.z = __low2float(accs[1]); o0.w = __high2float(accs[1]);
        o1.x = __low2float(accs[2]); o1.y = __high2float(accs[2]);
        o1.z = __low2float(accs[3]); o1.w = __high2float(accs[3]);
        float* orow = out + (size_t)row * OUT_COLS + ((lane & 31) << 3);
        *(float4*)orow = o0;
        *(float4*)(orow + 4) = o1;
    }
}

// ---------------- fallback (binary search, f32 weights), if ws too small ----------------
__global__ __launch_bounds__(256, 8)
void fallback_kernel(const int* __restrict__ batch_idx,
                     const int* __restrict__ active_idx,
                     const float* __restrict__ values,
                     const int* __restrict__ f_table,
                     const float* __restrict__ weights,
                     float* __restrict__ out,
                     int nnz, int N)
{
    const int wave = threadIdx.x >> 6;
    const int lane = threadIdx.x & 63;
    const int row  = blockIdx.x * 4 + wave;
    if (row >= N) return;

    int lo1 = 0, hi1 = nnz, lo2 = 0, hi2 = nnz;
    while ((lo1 < hi1) | (lo2 < hi2)) {
        if (lo1 < hi1) { int m = (lo1 + hi1) >> 1; if (batch_idx[m] < row) lo1 = m + 1; else hi1 = m; }
        if (lo2 < hi2) { int m = (lo2 + hi2) >> 1; if (batch_idx[m] < row + 1) lo2 = m + 1; else hi2 = m; }
    }
    float4 acc = make_float4(0.f, 0.f, 0.f, 0.f);
    const float* __restrict__ wcol = weights + (lane << 2);
    for (int base = lo1; base < lo2; base += 64) {
        const int c = min(lo2 - base, 64);
        float v_l = 0.f; int f_l = 0;
        if (lane < c) { const int k = base + lane; v_l = values[k]; f_l = f_table[active_idx[k]]; }
        for (int j = 0; j < c; ++j) {
            const float v = __shfl(v_l, j);
            const int   f = __shfl(f_l, j);
            const float4 w = *(const float4*)(wcol + f * OUT_COLS);
            acc.x = fmaf(v, w.x, acc.x);
            acc.y = fmaf(v, w.y, acc.y);
            acc.z = fmaf(v, w.z, acc.z);
            acc.w = fmaf(v, w.w, acc.w);
        }
    }
    *(float4*)(out + row * OUT_COLS + (lane << 2)) = acc;
}

extern "C" void kernel_launch(void* const* d_in, const int* in_sizes, int n_in,
                              void* d_out, int out_size, void* d_ws, size_t ws_size,
                              hipStream_t stream) {
    const int*   batch_idx  = (const int*)d_in[0];
    const int*   active_idx = (const int*)d_in[1];
    const float* values     = (const float*)d_in[2];
    const int*   f_table    = (const int*)d_in[3];
    const float* weights    = (const float*)d_in[4];
    float*       out        = (float*)d_out;

    const int nnz = in_sizes[0];
    const int N   = out_size / OUT_COLS;  // 16384

    // ws layout: offsets[N+1] | wh[NW] f16 | pairs[nnz] u32 | 256 B over-read slack
    const size_t off_bytes = (size_t)(N + 1) * sizeof(int);
    const size_t wh_off    = (off_bytes + 15) & ~(size_t)15;
    const size_t pairs_off = (wh_off + (size_t)NW * 2 + 15) & ~(size_t)15;
    const size_t need      = pairs_off + (size_t)nnz * sizeof(unsigned) + 256;

    const int grid_rows = (N + WAVES_PER_BLOCK - 1) / WAVES_PER_BLOCK;

    if (ws_size >= need) {
        int*      offsets = (int*)d_ws;
        __half*   wh      = (__half*)((char*)d_ws + wh_off);
        unsigned* pairs   = (unsigned*)((char*)d_ws + pairs_off);

        const int work = (nnz > NW) ? nnz : NW;
        build_kernel<<<(work + 255) / 256, 256, 0, stream>>>(
            batch_idx, active_idx, values, f_table, weights,
            offsets, pairs, wh, nnz, N);
        gemm_kernel<<<grid_rows, BLOCK_THREADS, 0, stream>>>(offsets, pairs, wh, out, N);
    } else {
        fallback_kernel<<<grid_rows, 256, 0, stream>>>(
            batch_idx, active_idx, values, f_table, weights, out, nnz, N);
    }
}